// Round 1
// baseline (341.977 us; speedup 1.0000x reference)
//
#include <hip/hip_runtime.h>
#include <hip/hip_bf16.h>

#define DEV __device__ __forceinline__

typedef __attribute__((ext_vector_type(8))) short bf16x8;
typedef __attribute__((ext_vector_type(4))) float f32x4;
typedef __attribute__((ext_vector_type(4))) short short4v;

DEV short f2bf(float f) {
    union { float f; unsigned u; } x; x.f = f;
    unsigned u = x.u;
    unsigned r = (u + 0x7fffu + ((u >> 16) & 1u)) >> 16;
    return (short)r;
}

// ---------------- prep kernels ----------------

__global__ __launch_bounds__(256) void k_cast(const float* __restrict__ in,
                                              short* __restrict__ out, int n4) {
    int i = blockIdx.x * 256 + threadIdx.x;
    if (i >= n4) return;
    float4 v = ((const float4*)in)[i];
    short4v o;
    o[0] = f2bf(v.x); o[1] = f2bf(v.y); o[2] = f2bf(v.z); o[3] = f2bf(v.w);
    ((short4v*)out)[i] = o;
}

// WqkvT[n][d] for n in [0,3072): part p=n>>10, h=(n&1023)>>6, k=n&63 : = W_p[h][d][k]
__global__ __launch_bounds__(256) void k_qkv_pack(const float* __restrict__ Wq,
                                                  const float* __restrict__ Wk,
                                                  const float* __restrict__ Wv,
                                                  short* __restrict__ WT) {
    int e = blockIdx.x * 256 + threadIdx.x;   // < 3*1024*1024
    int n = e >> 10, d = e & 1023;
    int p = n >> 10, c1 = n & 1023;
    int h = c1 >> 6, k = c1 & 63;
    const float* W = (p == 0) ? Wq : (p == 1) ? Wk : Wv;
    WT[e] = f2bf(W[(((size_t)h << 10) + d) * 64 + k]);
}

// out[c][r] = in[r][c], R = 1<<logR rows, C cols
__global__ __launch_bounds__(256) void k_transpose(const float* __restrict__ in,
                                                   short* __restrict__ out,
                                                   int logR, int C) {
    int e = blockIdx.x * 256 + threadIdx.x;   // < R*C
    int R1 = (1 << logR) - 1;
    int c = e >> logR, r = e & R1;
    out[e] = f2bf(in[(size_t)r * C + c]);
}

// ---------------- GEMM: C = A[M,K] * BT[N,K]^T ----------------
// block: 256 thr = 4 waves (2x2), tile 128x128, wave tile 64x64, BK=64
// MODE 0: QKV scatter epilogue (bias f0/f1/f2 -> o0=Q, o1=K, o2=VT)
// MODE 1: f32 out = acc + f0[col] + resid[row*N+col]  -> o0
// MODE 2: bf16 out = relu(acc + f0[col])              -> o0
template <int MODE>
__global__ __launch_bounds__(256) void k_gemm(
    const short* __restrict__ A, const short* __restrict__ BT, int K,
    const float* __restrict__ f0, const float* __restrict__ f1,
    const float* __restrict__ f2, const float* __restrict__ resid,
    void* __restrict__ o0, void* __restrict__ o1, void* __restrict__ o2) {
    __shared__ short Al[128][72];
    __shared__ short Bl[128][72];
    const int t = threadIdx.x;
    const int l = t & 63, w = t >> 6;
    const int l16 = l & 15, lg = l >> 4;
    const int wm = w >> 1, wn = w & 1;
    const int bn = blockIdx.x, bm = blockIdx.y;
    f32x4 acc[4][4] = {};
    const short* Ab = A + (size_t)bm * 128 * K;
    const short* Bb = BT + (size_t)bn * 128 * K;
    const int sr = t >> 3, sc = (t & 7) * 8;

    for (int k0 = 0; k0 < K; k0 += 64) {
#pragma unroll
        for (int it = 0; it < 4; ++it) {
            int rr = sr + it * 32;
            *(bf16x8*)&Al[rr][sc] = *(const bf16x8*)(Ab + (size_t)rr * K + k0 + sc);
            *(bf16x8*)&Bl[rr][sc] = *(const bf16x8*)(Bb + (size_t)rr * K + k0 + sc);
        }
        __syncthreads();
#pragma unroll
        for (int kk = 0; kk < 2; ++kk) {
            bf16x8 af[4], bfv[4];
#pragma unroll
            for (int i = 0; i < 4; ++i)
                af[i] = *(const bf16x8*)&Al[wm * 64 + i * 16 + l16][kk * 32 + lg * 8];
#pragma unroll
            for (int j = 0; j < 4; ++j)
                bfv[j] = *(const bf16x8*)&Bl[wn * 64 + j * 16 + l16][kk * 32 + lg * 8];
#pragma unroll
            for (int i = 0; i < 4; ++i)
#pragma unroll
                for (int j = 0; j < 4; ++j)
                    acc[i][j] = __builtin_amdgcn_mfma_f32_16x16x32_bf16(
                        af[i], bfv[j], acc[i][j], 0, 0, 0);
        }
        __syncthreads();
    }

    const int N = gridDim.x * 128;
#pragma unroll
    for (int i = 0; i < 4; ++i) {
#pragma unroll
        for (int rr = 0; rr < 4; ++rr) {
            int row = bm * 128 + wm * 64 + i * 16 + lg * 4 + rr;
#pragma unroll
            for (int j = 0; j < 4; ++j) {
                int col = bn * 128 + wn * 64 + j * 16 + l16;
                float v = acc[i][j][rr];
                if constexpr (MODE == 0) {
                    int p = col >> 10, c1 = col & 1023;
                    int hh = c1 >> 6, dk = c1 & 63;
                    const float* bias = (p == 0) ? f0 : (p == 1) ? f1 : f2;
                    short bv = f2bf(v + bias[c1]);
                    int b = row >> 10, s = row & 1023;
                    if (p == 2)
                        ((short*)o2)[(((size_t)(b * 16 + hh) * 64 + dk) << 10) + s] = bv;
                    else {
                        short* dst = (p == 0) ? (short*)o0 : (short*)o1;
                        dst[(((size_t)(b * 16 + hh) << 10) + s) * 64 + dk] = bv;
                    }
                } else if constexpr (MODE == 1) {
                    size_t idx = (size_t)row * N + col;
                    ((float*)o0)[idx] = v + f0[col] + resid[idx];
                } else {
                    size_t idx = (size_t)row * N + col;
                    float y = v + f0[col];
                    ((short*)o0)[idx] = f2bf(y > 0.f ? y : 0.f);
                }
            }
        }
    }
}

// ---------------- flash attention ----------------
// grid (64, 16): blockIdx.x = b*16+h, blockIdx.y = q-block of 64 rows
// 4 waves, each owns 16 q rows. Q,K: [B,H,S,64] bf16; VT: [B,H,64,S] bf16
__global__ __launch_bounds__(256) void k_attn(const short* __restrict__ Q,
                                              const short* __restrict__ Kt,
                                              const short* __restrict__ VT,
                                              short* __restrict__ O) {
    __shared__ short Kl[64][72];
    __shared__ short Vl[64][72];
    __shared__ short Pl[4][16][72];
    const int bh = blockIdx.x;
    const int qb = blockIdx.y;
    const int t = threadIdx.x;
    const int w = t >> 6, l = t & 63;
    const int l16 = l & 15, lg = l >> 4;

    const short* Qb = Q + ((size_t)bh * 1024 + qb * 64 + w * 16 + l16) * 64 + lg * 8;
    bf16x8 qf0 = *(const bf16x8*)Qb;
    bf16x8 qf1 = *(const bf16x8*)(Qb + 32);

    float m[4] = {-1e30f, -1e30f, -1e30f, -1e30f};
    float ls[4] = {0.f, 0.f, 0.f, 0.f};
    f32x4 oacc[4] = {};

    const int sr = t >> 3, sc = (t & 7) * 8;
    for (int t0 = 0; t0 < 1024; t0 += 64) {
#pragma unroll
        for (int it = 0; it < 2; ++it) {
            int rr = sr + it * 32;
            *(bf16x8*)&Kl[rr][sc] =
                *(const bf16x8*)(Kt + ((size_t)bh * 1024 + t0 + rr) * 64 + sc);
            *(bf16x8*)&Vl[rr][sc] =
                *(const bf16x8*)(VT + ((size_t)bh * 64 + rr) * 1024 + t0 + sc);
        }
        __syncthreads();

        f32x4 s[4];
#pragma unroll
        for (int n = 0; n < 4; ++n) {
            f32x4 a = {0.f, 0.f, 0.f, 0.f};
            bf16x8 kf0 = *(const bf16x8*)&Kl[n * 16 + l16][lg * 8];
            bf16x8 kf1 = *(const bf16x8*)&Kl[n * 16 + l16][32 + lg * 8];
            a = __builtin_amdgcn_mfma_f32_16x16x32_bf16(qf0, kf0, a, 0, 0, 0);
            a = __builtin_amdgcn_mfma_f32_16x16x32_bf16(qf1, kf1, a, 0, 0, 0);
            s[n] = a * 0.125f;
        }
#pragma unroll
        for (int r = 0; r < 4; ++r) {
            float mx = fmaxf(fmaxf(s[0][r], s[1][r]), fmaxf(s[2][r], s[3][r]));
            mx = fmaxf(mx, __shfl_xor(mx, 1));
            mx = fmaxf(mx, __shfl_xor(mx, 2));
            mx = fmaxf(mx, __shfl_xor(mx, 4));
            mx = fmaxf(mx, __shfl_xor(mx, 8));
            float mn = fmaxf(m[r], mx);
            float al = __expf(m[r] - mn);
            m[r] = mn;
            float su = 0.f;
#pragma unroll
            for (int n = 0; n < 4; ++n) {
                float p = __expf(s[n][r] - mn);
                s[n][r] = p;
                su += p;
            }
            su += __shfl_xor(su, 1);
            su += __shfl_xor(su, 2);
            su += __shfl_xor(su, 4);
            su += __shfl_xor(su, 8);
            ls[r] = ls[r] * al + su;
#pragma unroll
            for (int n = 0; n < 4; ++n) oacc[n][r] *= al;
        }
#pragma unroll
        for (int n = 0; n < 4; ++n)
#pragma unroll
            for (int r = 0; r < 4; ++r)
                Pl[w][lg * 4 + r][n * 16 + l16] = f2bf(s[n][r]);
        __syncthreads();
#pragma unroll
        for (int n = 0; n < 4; ++n) {
#pragma unroll
            for (int kk = 0; kk < 2; ++kk) {
                bf16x8 pa = *(const bf16x8*)&Pl[w][l16][kk * 32 + lg * 8];
                bf16x8 vb = *(const bf16x8*)&Vl[n * 16 + l16][kk * 32 + lg * 8];
                oacc[n] = __builtin_amdgcn_mfma_f32_16x16x32_bf16(pa, vb, oacc[n], 0, 0, 0);
            }
        }
        __syncthreads();
    }

    const int b = bh >> 4, h = bh & 15;
#pragma unroll
    for (int r = 0; r < 4; ++r) {
        float inv = 1.f / ls[r];
        size_t row = (size_t)(b * 1024 + qb * 64 + w * 16 + lg * 4 + r);
#pragma unroll
        for (int n = 0; n < 4; ++n)
            O[row * 1024 + h * 64 + n * 16 + l16] = f2bf(oacc[n][r] * inv);
    }
}

// ---------------- layernorm (one row of 1024 per block) ----------------
__global__ __launch_bounds__(256) void k_ln(const float* __restrict__ in,
                                            const float* __restrict__ g,
                                            const float* __restrict__ be,
                                            float* __restrict__ of,
                                            short* __restrict__ ob) {
    const int row = blockIdx.x, t = threadIdx.x;
    float4 x = ((const float4*)(in + ((size_t)row << 10)))[t];
    float s = x.x + x.y + x.z + x.w;
    float s2 = x.x * x.x + x.y * x.y + x.z * x.z + x.w * x.w;
#pragma unroll
    for (int mm = 1; mm < 64; mm <<= 1) {
        s += __shfl_xor(s, mm);
        s2 += __shfl_xor(s2, mm);
    }
    __shared__ float red[8];
    if ((t & 63) == 0) { red[t >> 6] = s; red[4 + (t >> 6)] = s2; }
    __syncthreads();
    s = red[0] + red[1] + red[2] + red[3];
    s2 = red[4] + red[5] + red[6] + red[7];
    float mean = s * (1.f / 1024.f);
    float var = s2 * (1.f / 1024.f) - mean * mean;
    float rstd = rsqrtf(var + 1e-5f);
    int c = t * 4;
    float4 y;
    y.x = (x.x - mean) * rstd * g[c + 0] + be[c + 0];
    y.y = (x.y - mean) * rstd * g[c + 1] + be[c + 1];
    y.z = (x.z - mean) * rstd * g[c + 2] + be[c + 2];
    y.w = (x.w - mean) * rstd * g[c + 3] + be[c + 3];
    if (of) ((float4*)(of + ((size_t)row << 10)))[t] = y;
    if (ob) {
        short4v o;
        o[0] = f2bf(y.x); o[1] = f2bf(y.y); o[2] = f2bf(y.z); o[3] = f2bf(y.w);
        ((short4v*)(ob + ((size_t)row << 10)))[t] = o;
    }
}

// ---------------- host ----------------
extern "C" void kernel_launch(void* const* d_in, const int* in_sizes, int n_in,
                              void* d_out, int out_size, void* d_ws, size_t ws_size,
                              hipStream_t stream) {
    (void)in_sizes; (void)n_in; (void)out_size; (void)ws_size;
    const float* src = (const float*)d_in[0];
    const float* Wq  = (const float*)d_in[1];
    const float* bq  = (const float*)d_in[2];
    const float* Wk  = (const float*)d_in[3];
    const float* bk  = (const float*)d_in[4];
    const float* Wv  = (const float*)d_in[5];
    const float* bv  = (const float*)d_in[6];
    const float* Wo  = (const float*)d_in[7];
    const float* bo  = (const float*)d_in[8];
    const float* g1  = (const float*)d_in[9];
    const float* be1 = (const float*)d_in[10];
    const float* W1  = (const float*)d_in[11];
    const float* b1  = (const float*)d_in[12];
    const float* W2  = (const float*)d_in[13];
    const float* b2  = (const float*)d_in[14];
    const float* g2  = (const float*)d_in[15];
    const float* be2 = (const float*)d_in[16];

    char* ws = (char*)d_ws;
    const size_t MB8 = 8388608;
    size_t off = 0;
    // union region 0..32MB: {srcbf, Qb, Kb, VTb} later reused as h1 (GEMM3 out)
    short* srcbf = (short*)(ws + 0);          // 8MB, also Obuf after attn
    short* Qb    = (short*)(ws + MB8);        // 8MB
    short* Kb    = (short*)(ws + 2 * MB8);    // 8MB
    short* VTb   = (short*)(ws + 3 * MB8);    // 8MB
    short* h1    = (short*)(ws + 0);          // 32MB alias (all dead by GEMM3)
    short* Obuf  = srcbf;                     // 8MB alias (srcbf dead after GEMM1)
    off = 4 * MB8;
    short* WqkvT = (short*)(ws + off); off += 6291456;   // [3072][1024] bf16
    short* WoT   = (short*)(ws + off); off += 2097152;   // [1024][1024] bf16
    short* W1T   = (short*)(ws + off); off += 8388608;   // [4096][1024] bf16
    short* W2T   = (short*)(ws + off); off += 8388608;   // [1024][4096] bf16
    float* xres  = (float*)(ws + off); off += 16777216;  // [4096][1024] f32, reused as ffnres
    float* xf    = (float*)(ws + off); off += 16777216;  // [4096][1024] f32
    short* xbf   = (short*)(ws + off); off += 8388608;   // [4096][1024] bf16
    float* ffnres = xres;

    // prep
    k_cast<<<4096, 256, 0, stream>>>(src, srcbf, 1048576);
    k_qkv_pack<<<12288, 256, 0, stream>>>(Wq, Wk, Wv, WqkvT);
    k_transpose<<<4096, 256, 0, stream>>>(Wo, WoT, 10, 1024);
    k_transpose<<<16384, 256, 0, stream>>>(W1, W1T, 10, 4096);
    k_transpose<<<16384, 256, 0, stream>>>(W2, W2T, 12, 1024);
    // QKV projection (M=4096, N=3072, K=1024)
    k_gemm<0><<<dim3(24, 32), 256, 0, stream>>>(srcbf, WqkvT, 1024, bq, bk, bv,
                                                nullptr, Qb, Kb, VTb);
    // attention
    k_attn<<<dim3(64, 16), 256, 0, stream>>>(Qb, Kb, VTb, Obuf);
    // output projection + residual (M=4096, N=1024, K=1024)
    k_gemm<1><<<dim3(8, 32), 256, 0, stream>>>(Obuf, WoT, 1024, bo, nullptr, nullptr,
                                               src, xres, nullptr, nullptr);
    k_ln<<<4096, 256, 0, stream>>>(xres, g1, be1, xf, xbf);
    // FFN up + relu (M=4096, N=4096, K=1024)
    k_gemm<2><<<dim3(32, 32), 256, 0, stream>>>(xbf, W1T, 1024, b1, nullptr, nullptr,
                                                nullptr, h1, nullptr, nullptr);
    // FFN down + residual (M=4096, N=1024, K=4096)
    k_gemm<1><<<dim3(8, 32), 256, 0, stream>>>(h1, W2T, 4096, b2, nullptr, nullptr,
                                               xf, ffnres, nullptr, nullptr);
    k_ln<<<4096, 256, 0, stream>>>(ffnres, g2, be2, (float*)d_out, nullptr);
}